// Round 1
// baseline (9.750 us; speedup 1.0000x reference)
//
#include <hip/hip_runtime.h>
#include <math.h>

// DistanceTransform (kornia-style) on (B=16, C=1, H=128, W=128) fp32.
//
// The reference's 128-iteration lax.scan provably reduces to iteration 0 only:
//   - boundary is pointwise monotone non-decreasing (values only replaced by 1,
//     image in (0,1)), and the 3x3 kernel has non-negative weights, so
//     conv(boundary) is monotone non-decreasing per pixel across iterations.
//   - a pixel contributes at iter i iff conv_i < 1 (cdt > 0). If it contributes
//     at i=0 its boundary becomes 1 -> conv >= 1 (center weight = exp(0) = 1)
//     forever -> never again. If conv_0 >= 1, monotonicity gives conv_i >= 1
//     forever -> never contributes.
//   - at i=0 the offset term is (0*3)//2 = 0.
// Hence: out = relu(-h * log(conv3x3_replicate(image))). Later iterations add
// exactly 0.0f (conv > 0 always -> cdt finite -> cdt * 0 == 0).

#define BATCH 16
#define HEIGHT 128
#define WIDTH 128
#define H_PARAM 0.35f

__global__ __launch_bounds__(256) void DistanceTransform_66683662238011_kernel(
    const float* __restrict__ img, float* __restrict__ out) {
    const int idx = blockIdx.x * 256 + threadIdx.x;  // 0 .. 262143
    const int x = idx & (WIDTH - 1);
    const int y = (idx >> 7) & (HEIGHT - 1);
    const int b = idx >> 14;

    const float* __restrict__ p = img + (b << 14);

    const int xm = (x > 0) ? x - 1 : 0;
    const int xp = (x < WIDTH - 1) ? x + 1 : WIDTH - 1;
    const int ym = (y > 0) ? y - 1 : 0;
    const int yp = (y < HEIGHT - 1) ? y + 1 : HEIGHT - 1;

    // kernel weights, matching the reference's fp32 construction:
    //   w1 = exp(-1/0.35), w2 = exp(-sqrt(2)/0.35), center = exp(0) = 1
    const float w1 = expf(-1.0f / H_PARAM);
    const float w2 = expf(-sqrtf(2.0f) / H_PARAM);

    const int rm = ym << 7, r0 = y << 7, rp = yp << 7;

    const float nw = p[rm + xm], nn = p[rm + x], ne = p[rm + xp];
    const float ww = p[r0 + xm], cc = p[r0 + x], ee = p[r0 + xp];
    const float sw = p[rp + xm], ss = p[rp + x], se = p[rp + xp];

    const float conv = cc
                     + w1 * (nn + ss + ww + ee)
                     + w2 * (nw + ne + sw + se);

    const float cdt = -H_PARAM * logf(conv);
    out[idx] = (cdt > 0.0f) ? cdt : 0.0f;
}

extern "C" void kernel_launch(void* const* d_in, const int* in_sizes, int n_in,
                              void* d_out, int out_size, void* d_ws, size_t ws_size,
                              hipStream_t stream) {
    const float* img = (const float*)d_in[0];
    float* out = (float*)d_out;
    const int total = BATCH * HEIGHT * WIDTH;  // 262144
    const int block = 256;
    const int grid = total / block;  // 1024
    DistanceTransform_66683662238011_kernel<<<grid, block, 0, stream>>>(img, out);
}